// Round 2
// baseline (156.734 us; speedup 1.0000x reference)
//
#include <hip/hip_runtime.h>

#define GYD 1024
#define GXD 1024
#define NUM_BEV 8

// broadcast lane 0's value to all lanes via SGPR
__device__ __forceinline__ float bcast0(float x) {
    return __int_as_float(__builtin_amdgcn_readfirstlane(__float_as_int(x)));
}
// reductions over lanes 0..31 (offsets <32 stay within the 32-lane half -> ds_swizzle)
__device__ __forceinline__ float rsum32(float x) {
#pragma unroll
    for (int o = 1; o < 32; o <<= 1) x += __shfl_xor(x, o, 64);
    return x;
}
__device__ __forceinline__ float rmax32(float x) {
#pragma unroll
    for (int o = 1; o < 32; o <<= 1) x = fmaxf(x, __shfl_xor(x, o, 64));
    return x;
}
__device__ __forceinline__ float rmin32(float x) {
#pragma unroll
    for (int o = 1; o < 32; o <<= 1) x = fminf(x, __shfl_xor(x, o, 64));
    return x;
}

// One wave per pillar; 4 pillars per 256-thread block.
__global__ __launch_bounds__(256) void pillar_kernel(
    const float4* __restrict__ vf,       // N*32 points (x,y,z,intensity)
    const float* __restrict__ W,         // 10 x 64 row-major
    const float* __restrict__ gammap, const float* __restrict__ betap,
    const float* __restrict__ rmean, const float* __restrict__ rvar,
    const int* __restrict__ npts_arr,
    const int* __restrict__ coords,      // N x 4: (b, zc, y, x)
    float* __restrict__ pillar_out,      // N*64
    float* __restrict__ bev_vals,        // N*8
    int* __restrict__ winner,            // bs*GY*GX
    int N, int bs)
{
    __shared__ float4 pts[4][32];
    const int wid  = threadIdx.x >> 6;
    const int lane = threadIdx.x & 63;
    const int n    = blockIdx.x * 4 + wid;
    const bool valid = (n < N);
    const int nn = valid ? n : 0;

    // per-channel constants (lane = channel); issue these loads early so their
    // latency overlaps the point load + reductions (all L2-hot after first waves)
    const int d = lane;
    const float w0 = W[d],        w1 = W[64 + d],  w2 = W[128 + d], w3 = W[192 + d];
    const float w4 = W[256 + d],  w5 = W[320 + d], w6 = W[384 + d];
    const float w7 = W[448 + d],  w8 = W[512 + d], w9 = W[576 + d];
    const float g  = gammap[d], bt = betap[d], rm = rmean[d], rv = rvar[d];

    const int npts = npts_arr[nn];
    const int cb   = coords[nn * 4 + 0];
    const int czi  = coords[nn * 4 + 1];
    const int cyi  = coords[nn * 4 + 2];
    const int cxi  = coords[nn * 4 + 3];
    // VX=VY=0.1, VZ=4.0; X_OFF=Y_OFF=0.05-51.2=-51.15; Z_OFF=2.0-3.0=-1.0
    const float cx = (float)cxi * 0.1f - 51.15f;
    const float cy = (float)cyi * 0.1f - 51.15f;
    const float cz = (float)czi * 4.0f - 1.0f;

    float4 v = make_float4(0.f, 0.f, 0.f, 0.f);
    bool pv = false;
    if (valid && lane < 32) {
        v = vf[(size_t)nn * 32 + lane];
        pv = (lane < npts);
    }
    // pad invalid point slots with point 0 (duplicates are max-neutral)
    float4 v0;
    v0.x = __shfl(v.x, 0, 64); v0.y = __shfl(v.y, 0, 64);
    v0.z = __shfl(v.z, 0, 64); v0.w = __shfl(v.w, 0, 64);
    if (valid && lane < 32) pts[wid][lane] = pv ? v : v0;

    const float m    = pv ? 1.f : 0.f;
    const float fn   = (float)npts;
    const float invn = 1.f / fn;

    // 12 independent width-32 reductions (interleavable by the scheduler)
    const float sx   = rsum32(v.x);          // unmasked (all 32 rows)
    const float sy   = rsum32(v.y);
    const float sz   = rsum32(v.z);
    const float smx  = rsum32(v.x * m);      // masked
    const float smy  = rsum32(v.y * m);
    const float smz  = rsum32(v.z * m);
    const float smI  = rsum32(v.w * m);
    const float sx2  = rsum32(v.x * v.x * m);
    const float sy2  = rsum32(v.y * v.y * m);
    const float sz2  = rsum32(v.z * v.z * m);
    const float maxz = rmax32(pv ? v.z : -1e6f);
    const float minz = rmin32(pv ? v.z :  1e6f);

    // broadcast the three unmasked means to SGPRs (needed by all channel lanes)
    const float mx_ = bcast0(sx) * invn;
    const float my_ = bcast0(sy) * invn;
    const float mz_ = bcast0(sz) * invn;

    __syncthreads();

    // folded per-channel affine: t = px*A + py*B + pz*C + I*D + base
    const float scale = g * rsqrtf(rv + 1e-3f);
    const float shift = bt - rm * scale;   // BN output of an all-zero (masked) row
    const float A = (w0 + w4 + w7) * scale;
    const float B = (w1 + w5 + w8) * scale;
    const float C = (w2 + w6 + w9) * scale;
    const float D = w3 * scale;
    const float E = -(mx_ * w4 + my_ * w5 + mz_ * w6 + cx * w7 + cy * w8 + cz * w9);
    const float base = fmaf(E, scale, shift);

    // fully-unrolled 32-point loop, 4 independent accumulators
    float a0 = -1e30f, a1 = -1e30f, a2 = -1e30f, a3 = -1e30f;
#pragma unroll
    for (int p = 0; p < 32; p += 4) {
        const float4 q0 = pts[wid][p + 0];
        const float4 q1 = pts[wid][p + 1];
        const float4 q2 = pts[wid][p + 2];
        const float4 q3 = pts[wid][p + 3];
        a0 = fmaxf(a0, fmaf(q0.x, A, fmaf(q0.y, B, fmaf(q0.z, C, fmaf(q0.w, D, base)))));
        a1 = fmaxf(a1, fmaf(q1.x, A, fmaf(q1.y, B, fmaf(q1.z, C, fmaf(q1.w, D, base)))));
        a2 = fmaxf(a2, fmaf(q2.x, A, fmaf(q2.y, B, fmaf(q2.z, C, fmaf(q2.w, D, base)))));
        a3 = fmaxf(a3, fmaf(q3.x, A, fmaf(q3.y, B, fmaf(q3.z, C, fmaf(q3.w, D, base)))));
    }
    float acc = fmaxf(fmaxf(a0, a1), fmaxf(a2, a3));
    if (npts < 32) acc = fmaxf(acc, shift);  // masked rows participate in the max
    acc = fmaxf(acc, 0.f);                   // ReLU commutes with max

    if (valid) {
        pillar_out[(size_t)n * 64 + lane] = acc;
        if (lane == 0) {
            const float pmx = smx * invn, pmy = smy * invn, pmz = smz * invn;
            const float vvx = fmaf(-pmx, pmx, sx2 * invn);
            const float vvy = fmaf(-pmy, pmy, sy2 * invn);
            const float vvz = fmaf(-pmz, pmz, sz2 * invn);
            float4* bvp = (float4*)&bev_vals[(size_t)n * 8];
            bvp[0] = make_float4(fn * (1.f / 32.f), smI * invn, pmz, maxz);
            bvp[1] = make_float4(maxz - minz, vvx, vvy, vvz);
            int b = cb < 0 ? 0 : (cb > bs - 1 ? bs - 1 : cb);
            const int cell = (b * GYD + cyi) * GXD + cxi;
            atomicMax(&winner[cell], n + 1);  // last-write-wins = max pillar index
        }
    }
}

// one thread per (pillar, bev-channel): 8x the parallelism of the latency-bound
// winner-check pass
__global__ __launch_bounds__(256) void scatter_kernel(
    const int* __restrict__ coords,
    const float* __restrict__ bev_vals,
    const int* __restrict__ winner,
    float* __restrict__ vox_bev,   // bs*8*GY*GX
    int N, int bs)
{
    const int t = blockIdx.x * blockDim.x + threadIdx.x;
    const int n = t >> 3, k = t & 7;
    if (n >= N) return;
    const int cb = coords[n * 4 + 0];
    const int y  = coords[n * 4 + 2];
    const int x  = coords[n * 4 + 3];
    const int b  = cb < 0 ? 0 : (cb > bs - 1 ? bs - 1 : cb);
    const int cell = (b * GYD + y) * GXD + x;
    if (winner[cell] == n + 1)
        vox_bev[(((size_t)b * NUM_BEV + k) * GYD + y) * GXD + x] = bev_vals[(size_t)n * 8 + k];
}

extern "C" void kernel_launch(void* const* d_in, const int* in_sizes, int n_in,
                              void* d_out, int out_size, void* d_ws, size_t ws_size,
                              hipStream_t stream) {
    const float4* vf    = (const float4*)d_in[0];
    const float* W      = (const float*)d_in[1];
    const float* gammap = (const float*)d_in[2];
    const float* betap  = (const float*)d_in[3];
    const float* rmean  = (const float*)d_in[4];
    const float* rvar   = (const float*)d_in[5];
    const int* npts     = (const int*)d_in[6];
    const int* coords   = (const int*)d_in[7];
    const int N  = in_sizes[6];
    const int bs = in_sizes[8];

    float* pillar_out = (float*)d_out;                        // N*64
    float* vox_bev    = (float*)d_out + (size_t)N * 64;       // bs*8*GY*GX

    int* winner     = (int*)d_ws;                             // bs*GY*GX ints
    float* bev_vals = (float*)((char*)d_ws + (size_t)bs * GYD * GXD * sizeof(int)); // N*8

    hipMemsetAsync(winner, 0, (size_t)bs * GYD * GXD * sizeof(int), stream);
    hipMemsetAsync(vox_bev, 0, (size_t)bs * NUM_BEV * GYD * GXD * sizeof(float), stream);

    const int blocksA = (N + 3) / 4;   // 4 pillars (waves) per block
    pillar_kernel<<<blocksA, 256, 0, stream>>>(vf, W, gammap, betap, rmean, rvar,
                                               npts, coords, pillar_out, bev_vals,
                                               winner, N, bs);
    const int blocksB = (N * NUM_BEV + 255) / 256;
    scatter_kernel<<<blocksB, 256, 0, stream>>>(coords, bev_vals, winner, vox_bev, N, bs);
}

// Round 3
// 135.948 us; speedup vs baseline: 1.1529x; 1.1529x over previous
//
#include <hip/hip_runtime.h>

#define GYD 1024
#define GXD 1024
#define NUM_BEV 8

__device__ __forceinline__ float rdlane(float x, int l) {
    return __int_as_float(__builtin_amdgcn_readlane(__float_as_int(x), l));
}
// half-local reductions (offsets <32 never cross the 32-lane halves)
__device__ __forceinline__ float rsum32(float x) {
#pragma unroll
    for (int o = 1; o < 32; o <<= 1) x += __shfl_xor(x, o, 64);
    return x;
}
__device__ __forceinline__ float rmax32(float x) {
#pragma unroll
    for (int o = 1; o < 32; o <<= 1) x = fmaxf(x, __shfl_xor(x, o, 64));
    return x;
}
__device__ __forceinline__ float rmin32(float x) {
#pragma unroll
    for (int o = 1; o < 32; o <<= 1) x = fminf(x, __shfl_xor(x, o, 64));
    return x;
}

// TWO pillars per wave: lanes 0-31 = pillar n0's 32 points, lanes 32-63 = pillar n0+1's.
// 4 waves/block -> 8 pillars/block, 5000 blocks.
__global__ __launch_bounds__(256) void pillar_kernel(
    const float4* __restrict__ vf,       // N*32 points (x,y,z,intensity)
    const float* __restrict__ W,         // 10 x 64 row-major
    const float* __restrict__ gammap, const float* __restrict__ betap,
    const float* __restrict__ rmeanp, const float* __restrict__ rvarp,
    const int* __restrict__ npts_arr,
    const int* __restrict__ coords,      // N x 4: (b, zc, y, x)
    float* __restrict__ pillar_out,      // N*64
    float* __restrict__ bev_vals,        // N*8
    int* __restrict__ winner,            // bs*GY*GX
    int N, int bs)
{
    __shared__ float4 pts[4][2][32];
    const int wid  = threadIdx.x >> 6;
    const int lane = threadIdx.x & 63;
    const int half = lane >> 5;
    const int sl   = lane & 31;
    const int n0   = blockIdx.x * 8 + wid * 2;
    const int n    = n0 + half;
    const bool valid = (n < N);
    const int nn = valid ? n : 0;

    // per-channel constants (lane = channel); issued early to overlap reductions
    const int d = lane;
    const float w0 = W[d],       w1 = W[64 + d],  w2 = W[128 + d], w3 = W[192 + d];
    const float w4 = W[256 + d], w5 = W[320 + d], w6 = W[384 + d];
    const float w7 = W[448 + d], w8 = W[512 + d], w9 = W[576 + d];
    const float g  = gammap[d], bt = betap[d], rm = rmeanp[d], rv = rvarp[d];

    const int npts = npts_arr[nn];                       // uniform per half
    const int4 crd = ((const int4*)coords)[nn];          // (b, zc, y, x)
    // VX=VY=0.1, VZ=4.0; X_OFF=Y_OFF=-51.15; Z_OFF=-1.0
    const float cx = (float)crd.w * 0.1f - 51.15f;
    const float cy = (float)crd.z * 0.1f - 51.15f;
    const float cz = (float)crd.y * 4.0f - 1.0f;

    float4 v = make_float4(0.f, 0.f, 0.f, 0.f);
    if (valid) v = vf[(size_t)nn * 32 + sl];             // 64 lanes -> 1KB coalesced
    const bool pv = sl < npts;
    // pad invalid slots with this half's point 0 (duplicates are max-neutral)
    const int src = half << 5;
    float4 v0;
    v0.x = __shfl(v.x, src, 64); v0.y = __shfl(v.y, src, 64);
    v0.z = __shfl(v.z, src, 64); v0.w = __shfl(v.w, src, 64);
    pts[wid][half][sl] = pv ? v : v0;

    const float m = pv ? 1.f : 0.f;
    // 12 independent half-local reductions (serve both pillars at once)
    const float sx   = rsum32(v.x);                      // unmasked
    const float sy   = rsum32(v.y);
    const float sz   = rsum32(v.z);
    const float smx  = rsum32(v.x * m);                  // masked
    const float smy  = rsum32(v.y * m);
    const float smz  = rsum32(v.z * m);
    const float smI  = rsum32(v.w * m);
    const float sx2  = rsum32(v.x * v.x * m);
    const float sy2  = rsum32(v.y * v.y * m);
    const float sz2  = rsum32(v.z * v.z * m);
    const float maxz = rmax32(pv ? v.z : -1e6f);
    const float minz = rmin32(pv ? v.z :  1e6f);

    __syncthreads();

    // folded per-channel affine: t = px*A + py*B + pz*C + I*D + base
    const float scale = g * rsqrtf(rv + 1e-3f);
    const float shift = fmaf(-rm, scale, bt);            // BN of an all-zero row
    const float A = (w0 + w4 + w7) * scale;
    const float B = (w1 + w5 + w8) * scale;
    const float C = (w2 + w6 + w9) * scale;
    const float D = w3 * scale;

    // channel phase: all 64 lanes = 64 channels, once per pillar
#pragma unroll
    for (int h = 0; h < 2; ++h) {
        const int L  = h << 5;
        const int nh = __builtin_amdgcn_readlane(npts, L);
        const float invnh = 1.f / (float)nh;
        const float mx = rdlane(sx, L) * invnh, my = rdlane(sy, L) * invnh, mz = rdlane(sz, L) * invnh;
        const float cxh = rdlane(cx, L), cyh = rdlane(cy, L), czh = rdlane(cz, L);
        const float E   = -(mx * w4 + my * w5 + mz * w6 + cxh * w7 + cyh * w8 + czh * w9);
        const float bse = fmaf(E, scale, shift);

        float a0 = -1e30f, a1 = -1e30f, a2 = -1e30f, a3 = -1e30f;
#pragma unroll
        for (int p = 0; p < 32; p += 4) {
            const float4 q0 = pts[wid][h][p + 0];
            const float4 q1 = pts[wid][h][p + 1];
            const float4 q2 = pts[wid][h][p + 2];
            const float4 q3 = pts[wid][h][p + 3];
            a0 = fmaxf(a0, fmaf(q0.x, A, fmaf(q0.y, B, fmaf(q0.z, C, fmaf(q0.w, D, bse)))));
            a1 = fmaxf(a1, fmaf(q1.x, A, fmaf(q1.y, B, fmaf(q1.z, C, fmaf(q1.w, D, bse)))));
            a2 = fmaxf(a2, fmaf(q2.x, A, fmaf(q2.y, B, fmaf(q2.z, C, fmaf(q2.w, D, bse)))));
            a3 = fmaxf(a3, fmaf(q3.x, A, fmaf(q3.y, B, fmaf(q3.z, C, fmaf(q3.w, D, bse)))));
        }
        float acc = fmaxf(fmaxf(a0, a1), fmaxf(a2, a3));
        if (nh < 32) acc = fmaxf(acc, shift);            // masked rows join the max
        acc = fmaxf(acc, 0.f);                           // ReLU commutes with max
        const int np_ = n0 + h;
        if (np_ < N) pillar_out[(size_t)np_ * 64 + lane] = acc;
    }

    // BEV stats: one leader lane per half (lanes 0 and 32)
    if (valid && sl == 0) {
        const float fn = (float)npts, invn = 1.f / fn;
        const float pmx = smx * invn, pmy = smy * invn, pmz = smz * invn;
        const float vvx = fmaf(-pmx, pmx, sx2 * invn);
        const float vvy = fmaf(-pmy, pmy, sy2 * invn);
        const float vvz = fmaf(-pmz, pmz, sz2 * invn);
        float4* bvp = (float4*)&bev_vals[(size_t)n * 8];
        bvp[0] = make_float4(fn * (1.f / 32.f), smI * invn, pmz, maxz);
        bvp[1] = make_float4(maxz - minz, vvx, vvy, vvz);
        const int b = crd.x < 0 ? 0 : (crd.x > bs - 1 ? bs - 1 : crd.x);
        atomicMax(&winner[(b * GYD + crd.z) * GXD + crd.w], n + 1);  // last-write-wins
    }
}

// One thread per BEV cell: writes ALL of vox_bev exactly once (zeros or winner's
// stats) -> replaces memset(67MB) + scatter pass.
__global__ __launch_bounds__(256) void bev_fill(
    const int* __restrict__ winner,
    const float* __restrict__ bev_vals,
    float* __restrict__ vox_bev, int bs)
{
    const int cell = blockIdx.x * 256 + threadIdx.x;     // < bs<<20
    const int w = winner[cell];
    float4 lo = make_float4(0.f, 0.f, 0.f, 0.f), hi = lo;
    if (w > 0) {
        const float4* bvp = (const float4*)&bev_vals[(size_t)(w - 1) * 8];
        lo = bvp[0]; hi = bvp[1];
    }
    const int b  = cell >> 20;                           // GY*GX = 1<<20
    const int yx = cell & ((1 << 20) - 1);
    float* basep = vox_bev + (((size_t)b * NUM_BEV) << 20) + yx;
    basep[(size_t)0 << 20] = lo.x; basep[(size_t)1 << 20] = lo.y;
    basep[(size_t)2 << 20] = lo.z; basep[(size_t)3 << 20] = lo.w;
    basep[(size_t)4 << 20] = hi.x; basep[(size_t)5 << 20] = hi.y;
    basep[(size_t)6 << 20] = hi.z; basep[(size_t)7 << 20] = hi.w;
}

extern "C" void kernel_launch(void* const* d_in, const int* in_sizes, int n_in,
                              void* d_out, int out_size, void* d_ws, size_t ws_size,
                              hipStream_t stream) {
    const float4* vf    = (const float4*)d_in[0];
    const float* W      = (const float*)d_in[1];
    const float* gammap = (const float*)d_in[2];
    const float* betap  = (const float*)d_in[3];
    const float* rmeanp = (const float*)d_in[4];
    const float* rvarp  = (const float*)d_in[5];
    const int* npts     = (const int*)d_in[6];
    const int* coords   = (const int*)d_in[7];
    const int N  = in_sizes[6];
    const int bs = in_sizes[8];

    float* pillar_out = (float*)d_out;                   // N*64
    float* vox_bev    = (float*)d_out + (size_t)N * 64;  // bs*8*GY*GX

    int* winner     = (int*)d_ws;                        // bs*GY*GX ints
    float* bev_vals = (float*)((char*)d_ws + (size_t)bs * GYD * GXD * sizeof(int));

    hipMemsetAsync(winner, 0, (size_t)bs * GYD * GXD * sizeof(int), stream);

    const int blocksA = (N + 7) / 8;                     // 8 pillars per block
    pillar_kernel<<<blocksA, 256, 0, stream>>>(vf, W, gammap, betap, rmeanp, rvarp,
                                               npts, coords, pillar_out, bev_vals,
                                               winner, N, bs);
    const int blocksB = (bs << 20) / 256;
    bev_fill<<<blocksB, 256, 0, stream>>>(winner, bev_vals, vox_bev, bs);
}